// Round 5
// baseline (266.452 us; speedup 1.0000x reference)
//
#include <hip/hip_runtime.h>
#include <math.h>

#define EPSV 1e-5f
#define SCALV 0.17677669529663687f   // 32^-0.5

typedef __attribute__((ext_vector_type(8))) short s16x8;
typedef __attribute__((ext_vector_type(8))) __bf16 bf8_t;
typedef __attribute__((ext_vector_type(4))) float f32x4;

__device__ inline unsigned short f2bfu(float f) {
  union { float f; unsigned u; } v; v.f = f;
  return (unsigned short)((v.u + 0x7FFFu + ((v.u >> 16) & 1u)) >> 16);
}

__device__ inline f32x4 mfma16(s16x8 a, s16x8 b, f32x4 c) {
  return __builtin_amdgcn_mfma_f32_16x16x32_bf16(
      __builtin_bit_cast(bf8_t, a), __builtin_bit_cast(bf8_t, b), c, 0, 0, 0);
}

__device__ inline void gll16(const void* g, const void* l) {
  __builtin_amdgcn_global_load_lds(
      (const __attribute__((address_space(1))) unsigned*)g,
      (__attribute__((address_space(3))) unsigned*)l, 16, 0, 0);
}

// ---------------------------------------------------------------------------
// 1) prep0 = transpose (src -> X fp32 + Xb bf16) + weight pack (fp32 -> bf16)
__global__ __launch_bounds__(256) void k_prep0(
    const float* __restrict__ src,
    const float* __restrict__ wqr, const float* __restrict__ wqc, const float* __restrict__ wv,
    const float* __restrict__ wo, const float* __restrict__ l1w, const float* __restrict__ l2w,
    float* __restrict__ X, short* __restrict__ Xb,
    short* __restrict__ Wcat, short* __restrict__ wob,
    short* __restrict__ l1b, short* __restrict__ l2b) {
  __shared__ float tile[32][33];
  int bid = blockIdx.x;
  int tid = threadIdx.x;
  if (bid < 1568) {
    int b = bid / 784;
    int rem = bid - b * 784;
    int cb = rem / 98, hwb = rem % 98;
    int hw0 = hwb * 32, c0 = cb * 32;
    int tx = tid & 31, ty = tid >> 5;
    for (int i = ty; i < 32; i += 8)
      tile[i][tx] = src[((size_t)(b * 256 + c0 + i)) * 3136 + hw0 + tx];
    __syncthreads();
    for (int i = ty; i < 32; i += 8) {
      float v = tile[tx][i];
      size_t idx = ((size_t)(b * 3136 + hw0 + i)) * 256 + c0 + tx;
      X[idx] = v;
      Xb[idx] = (short)f2bfu(v);
    }
  } else {
    int pb = bid - 1568;
    int seg = pb >> 8;
    int e = (((pb & 255) * 256) + tid) * 4;
    int cnt = (seg == 0) ? 196608 : (seg == 1) ? 65536 : 262144;
    if (e >= cnt) return;
    const float* sp;
    short* dp;
    if (seg == 0) {
      dp = Wcat + e;
      sp = (e < 65536) ? wqr + e : (e < 131072) ? wqc + (e - 65536) : wv + (e - 131072);
    } else if (seg == 1) { dp = wob + e; sp = wo + e; }
    else if (seg == 2)   { dp = l1b + e; sp = l1w + e; }
    else                 { dp = l2b + e; sp = l2w + e; }
    float4 v = *(const float4*)sp;
    uint2 p;
    p.x = (unsigned)f2bfu(v.x) | ((unsigned)f2bfu(v.y) << 16);
    p.y = (unsigned)f2bfu(v.z) | ((unsigned)f2bfu(v.w) << 16);
    *(uint2*)dp = p;
  }
}

// 2) Small projections with inlined h/w means (reads X rows, coalesced).
//    s=0: PRW = per@Wqr^T ; 1: PCW = pec@Wqc^T ;
//    s=2: KR = (mean_h X + per)@Wkr^T + bkr ; 3: KC = (mean_w X + pec)@Wkc^T + bkc
__global__ __launch_bounds__(256) void k_smallproj2(
    const float* __restrict__ per, const float* __restrict__ pec,
    const float* __restrict__ X,
    const float* __restrict__ wqr, const float* __restrict__ wqc,
    const float* __restrict__ wkr, const float* __restrict__ wkc,
    const float* __restrict__ bkr, const float* __restrict__ bkc,
    float* __restrict__ PRW, float* __restrict__ PCW,
    float* __restrict__ KR, float* __restrict__ KC) {
  __shared__ __align__(16) float inb[256];
  int s = blockIdx.x / 112;
  int r = blockIdx.x % 112;
  int j = threadIdx.x;
  const float* W;
  const float* bias = nullptr;
  float* out;
  float v;
  if (s == 0) {
    v = per[(size_t)r * 256 + j]; W = wqr; out = PRW;
  } else if (s == 1) {
    v = pec[(size_t)r * 256 + j]; W = wqc; out = PCW;
  } else if (s == 2) {
    int b = r / 56, w = r % 56;
    float sum = 0.f;
    for (int h = 0; h < 56; ++h)
      sum += X[((size_t)(b * 3136 + h * 56 + w)) * 256 + j];
    v = per[(size_t)r * 256 + j] + sum * (1.f / 56.f);
    W = wkr; bias = bkr; out = KR;
  } else {
    int b = r / 56, h = r % 56;
    float sum = 0.f;
    for (int w = 0; w < 56; ++w)
      sum += X[((size_t)(b * 3136 + h * 56 + w)) * 256 + j];
    v = pec[(size_t)r * 256 + j] + sum * (1.f / 56.f);
    W = wkc; bias = bkc; out = KC;
  }
  inb[j] = v;
  __syncthreads();
  const float* wrow = W + (size_t)j * 256;
  float acc = 0.f;
  #pragma unroll
  for (int c4 = 0; c4 < 64; ++c4) {
    float4 iv = *(const float4*)(&inb[c4 * 4]);
    float4 wv = *(const float4*)(wrow + c4 * 4);
    acc += iv.x * wv.x + iv.y * wv.y + iv.z * wv.z + iv.w * wv.w;
  }
  if (bias) acc += bias[j];
  out[(size_t)r * 256 + j] = acc;
}

// ---------------------------------------------------------------------------
// 3) 64x64-tile 2-phase pipelined MFMA GEMM core (verified R4 structure)
#define GEMM64_CORE(Aptr, Wptr, Kdim)                                           \
  __shared__ __align__(16) short Ls[2][2][4096];                                \
  int tid = threadIdx.x;                                                        \
  int wid = tid >> 6, lane = tid & 63;                                          \
  int ln15 = lane & 15, slot = lane >> 4;                                       \
  int m0 = blockIdx.x * 64, n0 = blockIdx.y * 64;                               \
  int l8 = lane >> 3, c8 = lane & 7;                                            \
  int csw = ((c8 ^ l8) << 4);                                                   \
  int K2 = (Kdim) * 2;                                                          \
  const char* Ag = (const char*)(Aptr) + (size_t)(m0 + wid * 16 + l8) * K2 + csw; \
  const char* Wg = (const char*)(Wptr) + (size_t)(n0 + wid * 16 + l8) * K2 + csw; \
  int u0 = __builtin_amdgcn_readfirstlane(wid * 2048);                          \
  int wm0 = (wid >> 1) << 5, wn0 = (wid & 1) << 5;                              \
  int xr = ln15 & 7;                                                            \
  f32x4 acc[2][2] = {};                                                         \
  int nt = (Kdim) >> 6;                                                         \
  {                                                                             \
    char* bA = (char*)&Ls[0][0][0];                                             \
    char* bB = (char*)&Ls[0][1][0];                                             \
    gll16(Ag, bA + u0);                                                         \
    gll16(Ag + (size_t)8 * K2, bA + u0 + 1024);                                 \
    gll16(Wg, bB + u0);                                                         \
    gll16(Wg + (size_t)8 * K2, bB + u0 + 1024);                                 \
  }                                                                             \
  __syncthreads();                                                              \
  for (int t = 0; t < nt; ++t) {                                                \
    int bf = t & 1;                                                             \
    if (t + 1 < nt) {                                                           \
      size_t ko = (size_t)(t + 1) * 128;                                        \
      char* bA = (char*)&Ls[bf ^ 1][0][0];                                      \
      char* bB = (char*)&Ls[bf ^ 1][1][0];                                      \
      gll16(Ag + ko, bA + u0);                                                  \
      gll16(Ag + ko + (size_t)8 * K2, bA + u0 + 1024);                          \
      gll16(Wg + ko, bB + u0);                                                  \
      gll16(Wg + ko + (size_t)8 * K2, bB + u0 + 1024);                          \
    }                                                                           \
    const char* LA = (const char*)&Ls[bf][0][0];                                \
    const char* LB = (const char*)&Ls[bf][1][0];                                \
    _Pragma("unroll")                                                           \
    for (int kc = 0; kc < 2; ++kc) {                                            \
      s16x8 af[2], bv2[2];                                                      \
      _Pragma("unroll")                                                         \
      for (int mf = 0; mf < 2; ++mf)                                            \
        af[mf] = *(const s16x8*)(LA + (wm0 + mf * 16 + ln15) * 128              \
                                  + (((kc * 4 + slot) ^ xr) << 4));             \
      _Pragma("unroll")                                                         \
      for (int nf = 0; nf < 2; ++nf)                                            \
        bv2[nf] = *(const s16x8*)(LB + (wn0 + nf * 16 + ln15) * 128             \
                                   + (((kc * 4 + slot) ^ xr) << 4));            \
      _Pragma("unroll")                                                         \
      for (int mf = 0; mf < 2; ++mf)                                            \
        _Pragma("unroll")                                                       \
        for (int nf = 0; nf < 2; ++nf)                                          \
          acc[mf][nf] = mfma16(af[mf], bv2[nf], acc[mf][nf]);                   \
    }                                                                           \
    __syncthreads();                                                            \
  }

template<int EPI>
__global__ __launch_bounds__(256) void k_gemm64p(
    const short* __restrict__ A, const short* __restrict__ W,
    const float* __restrict__ bias, float* __restrict__ outF,
    short* __restrict__ outB, int K, int N) {
  GEMM64_CORE(A, W, K)
  #pragma unroll
  for (int mf = 0; mf < 2; ++mf)
    #pragma unroll
    for (int nf = 0; nf < 2; ++nf) {
      int gc = n0 + wn0 + (nf << 4) + ln15;
      float bs = bias[gc];
      #pragma unroll
      for (int r = 0; r < 4; ++r) {
        int gr = m0 + wm0 + (mf << 4) + (slot << 2) + r;
        float v = acc[mf][nf][r] + bs;
        if (EPI == 0) outF[(size_t)gr * N + gc] = v;
        else          outB[(size_t)gr * N + gc] = (short)f2bfu(fmaxf(v, 0.f));
      }
    }
}

// Fused projection: Xb(6272,256) @ Wcat(768,256)^T, segmented epilogue
__global__ __launch_bounds__(256) void k_proj64p(
    const short* __restrict__ A, const short* __restrict__ W,
    const float* __restrict__ bqr, const float* __restrict__ bqc, const float* __restrict__ bv,
    const float* __restrict__ PRW, const float* __restrict__ PCW,
    float* __restrict__ QR, float* __restrict__ QC, short* __restrict__ Vt) {
  GEMM64_CORE(A, W, 256)
  int s = n0 >> 8;   // 0: QR, 1: QC, 2: V
  #pragma unroll
  for (int mf = 0; mf < 2; ++mf)
    #pragma unroll
    for (int nf = 0; nf < 2; ++nf) {
      f32x4 c = acc[mf][nf];
      int gc = n0 + wn0 + (nf << 4) + ln15;
      int jl = gc & 255;
      #pragma unroll
      for (int r = 0; r < 4; ++r) {
        int gr = m0 + wm0 + (mf << 4) + (slot << 2) + r;
        int bb = gr >= 3136;
        int q = gr - bb * 3136;
        if (s == 0) {
          int w = q % 56;
          QR[(size_t)gr * 256 + jl] =
              (c[r] + PRW[((size_t)(bb * 56 + w)) * 256 + jl] + bqr[jl]) * SCALV;
        } else if (s == 1) {
          int h = q / 56;
          QC[(size_t)gr * 256 + jl] =
              (c[r] + PCW[((size_t)(bb * 56 + h)) * 256 + jl] + bqc[jl]) * SCALV;
        } else {
          int nn = jl >> 5, d = jl & 31;
          int h = q / 56, w = q - h * 56;
          Vt[((size_t)((bb * 8 + nn) * 32 + d)) * 3584 + h * 64 + w] =
              (short)f2bfu(c[r] + bv[jl]);
        }
      }
    }
}

// ---------------------------------------------------------------------------
// 4) Fused attention: scores + softmax + RCDA recombination, per (b, n, 128q).
__global__ __launch_bounds__(256, 2) void k_fattn(
    const float* __restrict__ QR, const float* __restrict__ QC,
    const float* __restrict__ KR, const float* __restrict__ KC,
    const unsigned char* __restrict__ pm,
    const short* __restrict__ Vt, short* __restrict__ ATTb) {
  __shared__ __align__(16) float KsR[56][33];
  __shared__ __align__(16) float KsC[56][33];
  __shared__ __align__(16) short Ar[128 * 72];    // aw_row bf16, k padded/zeroed to 72
  __shared__ __align__(16) short Acs[128 * 56];   // aw_col bf16
  __shared__ __align__(16) short Vs[4 * 2176];    // 4 h-slabs of [32 d][68 w]
  int tid = threadIdx.x;
  int wid = tid >> 6, lane = tid & 63;
  int ln15 = lane & 15, slot = lane >> 4;
  int q0 = blockIdx.x * 128;
  int n = blockIdx.y, b = blockIdx.z;
  int bn = b * 8 + n;
  // stage K (row & col)
  for (int l = tid; l < 56 * 32; l += 256) {
    int w = l >> 5, d = l & 31;
    KsR[w][d] = KR[((size_t)(b * 56 + w) << 8) + (n << 5) + d];
    KsC[w][d] = KC[((size_t)(b * 56 + w) << 8) + (n << 5) + d];
  }
  __syncthreads();
  // ---- scores + softmax: wave wid handles local q in [wid*32, wid*32+32)
  bool mrow = (lane < 56) && (pm[(size_t)b * 3136 + lane] != 0);
  bool mcol = (lane < 56) && (pm[(size_t)b * 3136 + lane * 56] != 0);
  for (int i = 0; i < 32; ++i) {
    int ql = wid * 32 + i;
    int q = q0 + ql; if (q > 3135) q = 3135;
    size_t qoff = ((size_t)(b * 3136 + q) << 8) + (n << 5);
    // row scores
    {
      const float* Qg = QR + qoff;
      float sc = -INFINITY;
      if (lane < 56) {
        float s = 0.f;
        #pragma unroll
        for (int d4 = 0; d4 < 8; ++d4) {
          float4 qv = *(const float4*)(Qg + d4 * 4);
          s += qv.x * KsR[lane][d4 * 4 + 0] + qv.y * KsR[lane][d4 * 4 + 1]
             + qv.z * KsR[lane][d4 * 4 + 2] + qv.w * KsR[lane][d4 * 4 + 3];
        }
        if (mrow) s = -3.402823466e38f;
        sc = s;
      }
      float mx = sc;
      for (int o = 32; o; o >>= 1) mx = fmaxf(mx, __shfl_xor(mx, o));
      float e = (lane < 56) ? __expf(sc - mx) : 0.f;
      float ss = e;
      for (int o = 32; o; o >>= 1) ss += __shfl_xor(ss, o);
      if (lane < 56) {
        Ar[ql * 72 + lane] = (short)f2bfu(e / ss);
      } else {
        Ar[ql * 72 + lane] = 0;
        Ar[ql * 72 + lane + 8] = 0;
      }
    }
    // col scores
    {
      const float* Qg = QC + qoff;
      float sc = -INFINITY;
      if (lane < 56) {
        float s = 0.f;
        #pragma unroll
        for (int d4 = 0; d4 < 8; ++d4) {
          float4 qv = *(const float4*)(Qg + d4 * 4);
          s += qv.x * KsC[lane][d4 * 4 + 0] + qv.y * KsC[lane][d4 * 4 + 1]
             + qv.z * KsC[lane][d4 * 4 + 2] + qv.w * KsC[lane][d4 * 4 + 3];
        }
        if (mcol) s = -3.402823466e38f;
        sc = s;
      }
      float mx = sc;
      for (int o = 32; o; o >>= 1) mx = fmaxf(mx, __shfl_xor(mx, o));
      float e = (lane < 56) ? __expf(sc - mx) : 0.f;
      float ss = e;
      for (int o = 32; o; o >>= 1) ss += __shfl_xor(ss, o);
      if (lane < 56)
        Acs[ql * 56 + lane] = (short)f2bfu(e / ss);
    }
  }
  __syncthreads();
  // ---- recombination: TMP_h = V_h(d x w) @ Ar^T(w x q); out += Acs[q][h]*TMP
  s16x8 bfr[2][2];
  #pragma unroll
  for (int qf = 0; qf < 2; ++qf)
    #pragma unroll
    for (int kc = 0; kc < 2; ++kc)
      bfr[qf][kc] = *(const s16x8*)(Ar + (wid * 32 + qf * 16 + ln15) * 72
                                       + kc * 32 + slot * 8);
  const short* Vg = Vt + (size_t)bn * 32 * 3584;
  int sd = (tid >> 3) & 31, swp = tid & 7;
  const short* vsrc = Vg + (size_t)sd * 3584 + swp * 8;
  short* vdst = Vs + sd * 68 + swp * 8;
  s16x8 pre[4];
  #pragma unroll
  for (int i = 0; i < 4; ++i)
    pre[i] = *(const s16x8*)(vsrc + (size_t)i * 64);
  #pragma unroll
  for (int i = 0; i < 4; ++i)
    *(s16x8*)(vdst + i * 2176) = pre[i];
  __syncthreads();

  f32x4 oacc[2][2] = {};
  for (int hc = 0; hc < 14; ++hc) {
    if (hc < 13) {
      #pragma unroll
      for (int i = 0; i < 4; ++i)
        pre[i] = *(const s16x8*)(vsrc + (size_t)((hc + 1) * 4 + i) * 64);
    }
    #pragma unroll
    for (int hh = 0; hh < 4; ++hh) {
      int h = hc * 4 + hh;
      s16x8 af[2][2];
      #pragma unroll
      for (int df = 0; df < 2; ++df)
        #pragma unroll
        for (int kc = 0; kc < 2; ++kc)
          af[df][kc] = *(const s16x8*)(Vs + hh * 2176 + (df * 16 + ln15) * 68
                                          + kc * 32 + slot * 8);
      #pragma unroll
      for (int qf = 0; qf < 2; ++qf) {
        float acv = __uint_as_float(
            ((unsigned)(unsigned short)Acs[(wid * 32 + qf * 16 + ln15) * 56 + h]) << 16);
        #pragma unroll
        for (int df = 0; df < 2; ++df) {
          f32x4 tmp = {0.f, 0.f, 0.f, 0.f};
          tmp = mfma16(af[df][0], bfr[qf][0], tmp);
          tmp = mfma16(af[df][1], bfr[qf][1], tmp);
          oacc[df][qf][0] += acv * tmp[0];
          oacc[df][qf][1] += acv * tmp[1];
          oacc[df][qf][2] += acv * tmp[2];
          oacc[df][qf][3] += acv * tmp[3];
        }
      }
    }
    if (hc < 13) {
      __syncthreads();
      #pragma unroll
      for (int i = 0; i < 4; ++i)
        *(s16x8*)(vdst + i * 2176) = pre[i];
      __syncthreads();
    }
  }
  // transpose out via LDS (reuse Ar), then coalesced bf16 store
  __syncthreads();
  #pragma unroll
  for (int df = 0; df < 2; ++df)
    #pragma unroll
    for (int qf = 0; qf < 2; ++qf) {
      int qi = wid * 32 + qf * 16 + ln15;
      short4 pk;
      pk.x = (short)f2bfu(oacc[df][qf][0]);
      pk.y = (short)f2bfu(oacc[df][qf][1]);
      pk.z = (short)f2bfu(oacc[df][qf][2]);
      pk.w = (short)f2bfu(oacc[df][qf][3]);
      *(short4*)(Ar + qi * 36 + df * 16 + slot * 4) = pk;
    }
  __syncthreads();
  int q = tid >> 1, half = tid & 1;
  int qg = q0 + q;
  if (qg < 3136) {
    s16x8 v = *(const s16x8*)(Ar + q * 36 + half * 16);
    *(s16x8*)(ATTb + ((size_t)(b * 3136 + qg)) * 256 + n * 32 + half * 16) = v;
  }
}

// ---------------------------------------------------------------------------
// 5) LN1: XN1 = LayerNorm(Y + X) -> fp32 + bf16
__global__ __launch_bounds__(256) void k_ln1(
    const float* __restrict__ Y, const float* __restrict__ X,
    const float* __restrict__ g, const float* __restrict__ bb,
    float* __restrict__ XN1f, short* __restrict__ XN1b) {
  int tid = threadIdx.x;
  int row = blockIdx.x * 4 + (tid >> 6);
  int ln = tid & 63;
  size_t base = (size_t)row * 256 + ln * 4;
  float4 y = *(const float4*)(Y + base);
  float4 x = *(const float4*)(X + base);
  float v0 = y.x + x.x, v1 = y.y + x.y, v2 = y.z + x.z, v3 = y.w + x.w;
  float s = v0 + v1 + v2 + v3;
  float s2 = v0 * v0 + v1 * v1 + v2 * v2 + v3 * v3;
  for (int o = 32; o; o >>= 1) { s += __shfl_xor(s, o); s2 += __shfl_xor(s2, o); }
  float m = s * (1.f / 256.f);
  float inv = rsqrtf(fmaxf(s2 * (1.f / 256.f) - m * m, 0.f) + EPSV);
  float4 gg = *(const float4*)(g + ln * 4);
  float4 bv = *(const float4*)(bb + ln * 4);
  float4 o4;
  o4.x = (v0 - m) * inv * gg.x + bv.x;
  o4.y = (v1 - m) * inv * gg.y + bv.y;
  o4.z = (v2 - m) * inv * gg.z + bv.z;
  o4.w = (v3 - m) * inv * gg.w + bv.w;
  *(float4*)(XN1f + base) = o4;
  uint2 pk;
  pk.x = (unsigned)f2bfu(o4.x) | ((unsigned)f2bfu(o4.y) << 16);
  pk.y = (unsigned)f2bfu(o4.z) | ((unsigned)f2bfu(o4.w) << 16);
  *(uint2*)(XN1b + base) = pk;
}

// 6) LN2 + transposed store to (B,C,H,W)
__global__ __launch_bounds__(256) void k_ln2t(
    const float* __restrict__ Y2, const float* __restrict__ XN1,
    const float* __restrict__ g, const float* __restrict__ bb,
    float* __restrict__ out) {
  __shared__ float VL[16][257];
  int tid = threadIdx.x;
  int r0 = blockIdx.x * 16;
  for (int l = tid; l < 16 * 256; l += 256) {
    int r = l >> 8, c = l & 255;
    VL[r][c] = Y2[(size_t)(r0 + r) * 256 + c] + XN1[(size_t)(r0 + r) * 256 + c];
  }
  __syncthreads();
  int wv = tid >> 6, ln = tid & 63;
  for (int rr = wv; rr < 16; rr += 4) {
    float s = 0.f, s2 = 0.f;
    float vv[4];
    #pragma unroll
    for (int i = 0; i < 4; ++i) {
      float v = VL[rr][ln * 4 + i];
      vv[i] = v; s += v; s2 += v * v;
    }
    for (int o = 32; o; o >>= 1) { s += __shfl_xor(s, o); s2 += __shfl_xor(s2, o); }
    float m = s * (1.f / 256.f);
    float inv = rsqrtf(fmaxf(s2 * (1.f / 256.f) - m * m, 0.f) + EPSV);
    #pragma unroll
    for (int i = 0; i < 4; ++i) {
      int c = ln * 4 + i;
      VL[rr][c] = (vv[i] - m) * inv * g[c] + bb[c];
    }
  }
  __syncthreads();
  int b = r0 / 3136;
  int hw0 = r0 % 3136;
  int r = tid & 15, cg = tid >> 4;
  for (int it = 0; it < 16; ++it) {
    int c = it * 16 + cg;
    out[(size_t)(b * 256 + c) * 3136 + hw0 + r] = VL[r][c];
  }
}

// ---------------------------------------------------------------------------
extern "C" void kernel_launch(void* const* d_in, const int* in_sizes, int n_in,
                              void* d_out, int out_size, void* d_ws, size_t ws_size,
                              hipStream_t stream) {
  const float* src = (const float*)d_in[0];
  const unsigned char* pmask = (const unsigned char*)d_in[1];
  const float* per = (const float*)d_in[2];
  const float* pec = (const float*)d_in[3];
  const float* wqr = (const float*)d_in[4];
  const float* bqr = (const float*)d_in[5];
  const float* wqc = (const float*)d_in[6];
  const float* bqc = (const float*)d_in[7];
  const float* wkr = (const float*)d_in[8];
  const float* bkr = (const float*)d_in[9];
  const float* wkc = (const float*)d_in[10];
  const float* bkc = (const float*)d_in[11];
  const float* wv  = (const float*)d_in[12];
  const float* bv  = (const float*)d_in[13];
  const float* wo  = (const float*)d_in[14];
  const float* bo  = (const float*)d_in[15];
  const float* n1g = (const float*)d_in[16];
  const float* n1b = (const float*)d_in[17];
  const float* l1w = (const float*)d_in[18];
  const float* l1b = (const float*)d_in[19];
  const float* l2w = (const float*)d_in[20];
  const float* l2b = (const float*)d_in[21];
  const float* n2g = (const float*)d_in[22];
  const float* n2b = (const float*)d_in[23];

  float* ws = (float*)d_ws;
  float* X    = ws + 0;
  short* Xb   = (short*)(ws + 1605632);
  float* QR   = ws + 2408448;
  float* QC   = ws + 4014080;
  short* Vt   = (short*)(ws + 5619712);
  short* ATTb = (short*)(ws + 12156928);
  short* FFb  = (short*)(ws + 12959744);
  float* Y    = ws + 16171008;     // also Y2
  float* XN1f = ws + 17776640;
  short* XN1b = (short*)(ws + 19382272);
  float* PRW  = ws + 20242432;
  float* PCW  = ws + 20271104;
  float* KR   = ws + 20299776;
  float* KC   = ws + 20328448;
  short* Wcat = (short*)(ws + 20357120);
  short* wob  = (short*)(ws + 20455424);
  short* l1wb = (short*)(ws + 20488192);
  short* l2wb = (short*)(ws + 20619264);
  float* out = (float*)d_out;

  k_prep0<<<2592, 256, 0, stream>>>(src, wqr, wqc, wv, wo, l1w, l2w,
                                    X, Xb, Wcat, wob, l1wb, l2wb);
  k_smallproj2<<<448, 256, 0, stream>>>(per, pec, X, wqr, wqc, wkr, wkc,
                                        bkr, bkc, PRW, PCW, KR, KC);
  k_proj64p<<<dim3(98, 12), 256, 0, stream>>>(Xb, Wcat, bqr, bqc, bv,
                                              PRW, PCW, QR, QC, Vt);
  k_fattn<<<dim3(25, 8, 2), 256, 0, stream>>>(QR, QC, KR, KC, pmask, Vt, ATTb);
  k_gemm64p<0><<<dim3(98, 4), 256, 0, stream>>>(ATTb, wob, bo, Y, nullptr, 256, 256);
  k_ln1<<<1568, 256, 0, stream>>>(Y, X, n1g, n1b, XN1f, XN1b);
  k_gemm64p<1><<<dim3(98, 16), 256, 0, stream>>>(XN1b, l1wb, l1b, nullptr, FFb, 256, 1024);
  k_gemm64p<0><<<dim3(98, 4), 256, 0, stream>>>(FFb, l2wb, l2b, Y, nullptr, 1024, 256);
  k_ln2t<<<392, 256, 0, stream>>>(Y, XN1f, n2g, n2b, out);
}

// Round 7
// 213.158 us; speedup vs baseline: 1.2500x; 1.2500x over previous
//
#include <hip/hip_runtime.h>
#include <math.h>

#define EPSV 1e-5f
#define SCALV 0.17677669529663687f   // 32^-0.5

typedef __attribute__((ext_vector_type(8))) short s16x8;
typedef __attribute__((ext_vector_type(8))) __bf16 bf8_t;
typedef __attribute__((ext_vector_type(4))) float f32x4;

__device__ inline unsigned short f2bfu(float f) {
  union { float f; unsigned u; } v; v.f = f;
  return (unsigned short)((v.u + 0x7FFFu + ((v.u >> 16) & 1u)) >> 16);
}

__device__ inline f32x4 mfma16(s16x8 a, s16x8 b, f32x4 c) {
  return __builtin_amdgcn_mfma_f32_16x16x32_bf16(
      __builtin_bit_cast(bf8_t, a), __builtin_bit_cast(bf8_t, b), c, 0, 0, 0);
}

__device__ inline void gll16(const void* g, const void* l) {
  __builtin_amdgcn_global_load_lds(
      (const __attribute__((address_space(1))) unsigned*)g,
      (__attribute__((address_space(3))) unsigned*)l, 16, 0, 0);
}

// ---------------------------------------------------------------------------
// 1) prep0 = transpose (src -> X fp32 + Xb bf16) + weight pack (fp32 -> bf16)
__global__ __launch_bounds__(256) void k_prep0(
    const float* __restrict__ src,
    const float* __restrict__ wqr, const float* __restrict__ wqc, const float* __restrict__ wv,
    const float* __restrict__ wo, const float* __restrict__ l1w, const float* __restrict__ l2w,
    float* __restrict__ X, short* __restrict__ Xb,
    short* __restrict__ Wcat, short* __restrict__ wob,
    short* __restrict__ l1b, short* __restrict__ l2b) {
  __shared__ float tile[32][33];
  int bid = blockIdx.x;
  int tid = threadIdx.x;
  if (bid < 1568) {
    int b = bid / 784;
    int rem = bid - b * 784;
    int cb = rem / 98, hwb = rem % 98;
    int hw0 = hwb * 32, c0 = cb * 32;
    int tx = tid & 31, ty = tid >> 5;
    for (int i = ty; i < 32; i += 8)
      tile[i][tx] = src[((size_t)(b * 256 + c0 + i)) * 3136 + hw0 + tx];
    __syncthreads();
    for (int i = ty; i < 32; i += 8) {
      float v = tile[tx][i];
      size_t idx = ((size_t)(b * 3136 + hw0 + i)) * 256 + c0 + tx;
      X[idx] = v;
      Xb[idx] = (short)f2bfu(v);
    }
  } else {
    int pb = bid - 1568;
    int seg = pb >> 8;
    int e = (((pb & 255) * 256) + tid) * 4;
    int cnt = (seg == 0) ? 196608 : (seg == 1) ? 65536 : 262144;
    if (e >= cnt) return;
    const float* sp;
    short* dp;
    if (seg == 0) {
      dp = Wcat + e;
      sp = (e < 65536) ? wqr + e : (e < 131072) ? wqc + (e - 65536) : wv + (e - 131072);
    } else if (seg == 1) { dp = wob + e; sp = wo + e; }
    else if (seg == 2)   { dp = l1b + e; sp = l1w + e; }
    else                 { dp = l2b + e; sp = l2w + e; }
    float4 v = *(const float4*)sp;
    uint2 p;
    p.x = (unsigned)f2bfu(v.x) | ((unsigned)f2bfu(v.y) << 16);
    p.y = (unsigned)f2bfu(v.z) | ((unsigned)f2bfu(v.w) << 16);
    *(uint2*)dp = p;
  }
}

// 2) Small projections with inlined h/w means
__global__ __launch_bounds__(256) void k_smallproj2(
    const float* __restrict__ per, const float* __restrict__ pec,
    const float* __restrict__ X,
    const float* __restrict__ wqr, const float* __restrict__ wqc,
    const float* __restrict__ wkr, const float* __restrict__ wkc,
    const float* __restrict__ bkr, const float* __restrict__ bkc,
    float* __restrict__ PRW, float* __restrict__ PCW,
    float* __restrict__ KR, float* __restrict__ KC) {
  __shared__ __align__(16) float inb[256];
  int s = blockIdx.x / 112;
  int r = blockIdx.x % 112;
  int j = threadIdx.x;
  const float* W;
  const float* bias = nullptr;
  float* out;
  float v;
  if (s == 0) {
    v = per[(size_t)r * 256 + j]; W = wqr; out = PRW;
  } else if (s == 1) {
    v = pec[(size_t)r * 256 + j]; W = wqc; out = PCW;
  } else if (s == 2) {
    int b = r / 56, w = r % 56;
    float sum = 0.f;
    for (int h = 0; h < 56; ++h)
      sum += X[((size_t)(b * 3136 + h * 56 + w)) * 256 + j];
    v = per[(size_t)r * 256 + j] + sum * (1.f / 56.f);
    W = wkr; bias = bkr; out = KR;
  } else {
    int b = r / 56, h = r % 56;
    float sum = 0.f;
    for (int w = 0; w < 56; ++w)
      sum += X[((size_t)(b * 3136 + h * 56 + w)) * 256 + j];
    v = pec[(size_t)r * 256 + j] + sum * (1.f / 56.f);
    W = wkc; bias = bkc; out = KC;
  }
  inb[j] = v;
  __syncthreads();
  const float* wrow = W + (size_t)j * 256;
  float acc = 0.f;
  #pragma unroll
  for (int c4 = 0; c4 < 64; ++c4) {
    float4 iv = *(const float4*)(&inb[c4 * 4]);
    float4 wv = *(const float4*)(wrow + c4 * 4);
    acc += iv.x * wv.x + iv.y * wv.y + iv.z * wv.z + iv.w * wv.w;
  }
  if (bias) acc += bias[j];
  out[(size_t)r * 256 + j] = acc;
}

// ---------------------------------------------------------------------------
// 3) 64x64-tile 2-phase pipelined MFMA GEMM core (verified R4 structure)
#define GEMM64_CORE(Aptr, Wptr, Kdim)                                           \
  __shared__ __align__(16) short Ls[2][2][4096];                                \
  int tid = threadIdx.x;                                                        \
  int wid = tid >> 6, lane = tid & 63;                                          \
  int ln15 = lane & 15, slot = lane >> 4;                                       \
  int m0 = blockIdx.x * 64, n0 = blockIdx.y * 64;                               \
  int l8 = lane >> 3, c8 = lane & 7;                                            \
  int csw = ((c8 ^ l8) << 4);                                                   \
  int K2 = (Kdim) * 2;                                                          \
  const char* Ag = (const char*)(Aptr) + (size_t)(m0 + wid * 16 + l8) * K2 + csw; \
  const char* Wg = (const char*)(Wptr) + (size_t)(n0 + wid * 16 + l8) * K2 + csw; \
  int u0 = __builtin_amdgcn_readfirstlane(wid * 2048);                          \
  int wm0 = (wid >> 1) << 5, wn0 = (wid & 1) << 5;                              \
  int xr = ln15 & 7;                                                            \
  f32x4 acc[2][2] = {};                                                         \
  int nt = (Kdim) >> 6;                                                         \
  {                                                                             \
    char* bA = (char*)&Ls[0][0][0];                                             \
    char* bB = (char*)&Ls[0][1][0];                                             \
    gll16(Ag, bA + u0);                                                         \
    gll16(Ag + (size_t)8 * K2, bA + u0 + 1024);                                 \
    gll16(Wg, bB + u0);                                                         \
    gll16(Wg + (size_t)8 * K2, bB + u0 + 1024);                                 \
  }                                                                             \
  __syncthreads();                                                              \
  for (int t = 0; t < nt; ++t) {                                                \
    int bf = t & 1;                                                             \
    if (t + 1 < nt) {                                                           \
      size_t ko = (size_t)(t + 1) * 128;                                        \
      char* bA = (char*)&Ls[bf ^ 1][0][0];                                      \
      char* bB = (char*)&Ls[bf ^ 1][1][0];                                      \
      gll16(Ag + ko, bA + u0);                                                  \
      gll16(Ag + ko + (size_t)8 * K2, bA + u0 + 1024);                          \
      gll16(Wg + ko, bB + u0);                                                  \
      gll16(Wg + ko + (size_t)8 * K2, bB + u0 + 1024);                          \
    }                                                                           \
    const char* LA = (const char*)&Ls[bf][0][0];                                \
    const char* LB = (const char*)&Ls[bf][1][0];                                \
    _Pragma("unroll")                                                           \
    for (int kc = 0; kc < 2; ++kc) {                                            \
      s16x8 af[2], bv2[2];                                                      \
      _Pragma("unroll")                                                         \
      for (int mf = 0; mf < 2; ++mf)                                            \
        af[mf] = *(const s16x8*)(LA + (wm0 + mf * 16 + ln15) * 128              \
                                  + (((kc * 4 + slot) ^ xr) << 4));             \
      _Pragma("unroll")                                                         \
      for (int nf = 0; nf < 2; ++nf)                                            \
        bv2[nf] = *(const s16x8*)(LB + (wn0 + nf * 16 + ln15) * 128             \
                                   + (((kc * 4 + slot) ^ xr) << 4));            \
      _Pragma("unroll")                                                         \
      for (int mf = 0; mf < 2; ++mf)                                            \
        _Pragma("unroll")                                                       \
        for (int nf = 0; nf < 2; ++nf)                                          \
          acc[mf][nf] = mfma16(af[mf], bv2[nf], acc[mf][nf]);                   \
    }                                                                           \
    __syncthreads();                                                            \
  }

template<int EPI>
__global__ __launch_bounds__(256) void k_gemm64p(
    const short* __restrict__ A, const short* __restrict__ W,
    const float* __restrict__ bias, float* __restrict__ outF,
    short* __restrict__ outB, int K, int N) {
  GEMM64_CORE(A, W, K)
  #pragma unroll
  for (int mf = 0; mf < 2; ++mf)
    #pragma unroll
    for (int nf = 0; nf < 2; ++nf) {
      int gc = n0 + wn0 + (nf << 4) + ln15;
      float bs = bias[gc];
      #pragma unroll
      for (int r = 0; r < 4; ++r) {
        int gr = m0 + wm0 + (mf << 4) + (slot << 2) + r;
        float v = acc[mf][nf][r] + bs;
        if (EPI == 0) outF[(size_t)gr * N + gc] = v;
        else          outB[(size_t)gr * N + gc] = (short)f2bfu(fmaxf(v, 0.f));
      }
    }
}

__global__ __launch_bounds__(256) void k_proj64p(
    const short* __restrict__ A, const short* __restrict__ W,
    const float* __restrict__ bqr, const float* __restrict__ bqc, const float* __restrict__ bv,
    const float* __restrict__ PRW, const float* __restrict__ PCW,
    float* __restrict__ QR, float* __restrict__ QC, short* __restrict__ Vt) {
  GEMM64_CORE(A, W, 256)
  int s = n0 >> 8;   // 0: QR, 1: QC, 2: V
  #pragma unroll
  for (int mf = 0; mf < 2; ++mf)
    #pragma unroll
    for (int nf = 0; nf < 2; ++nf) {
      f32x4 c = acc[mf][nf];
      int gc = n0 + wn0 + (nf << 4) + ln15;
      int jl = gc & 255;
      #pragma unroll
      for (int r = 0; r < 4; ++r) {
        int gr = m0 + wm0 + (mf << 4) + (slot << 2) + r;
        int bb = gr >= 3136;
        int q = gr - bb * 3136;
        if (s == 0) {
          int w = q % 56;
          QR[(size_t)gr * 256 + jl] =
              (c[r] + PRW[((size_t)(bb * 56 + w)) * 256 + jl] + bqr[jl]) * SCALV;
        } else if (s == 1) {
          int h = q / 56;
          QC[(size_t)gr * 256 + jl] =
              (c[r] + PCW[((size_t)(bb * 56 + h)) * 256 + jl] + bqc[jl]) * SCALV;
        } else {
          int nn = jl >> 5, d = jl & 31;
          int h = q / 56, w = q - h * 56;
          Vt[((size_t)((bb * 8 + nn) * 32 + d)) * 3584 + h * 64 + w] =
              (short)f2bfu(c[r] + bv[jl]);
        }
      }
    }
}

// ---------------------------------------------------------------------------
// 4) Fused attention v2: MFMA scores + parallel softmax + RCDA recombination.
__global__ __launch_bounds__(256, 2) void k_fattn2(
    const float* __restrict__ QR, const float* __restrict__ QC,
    const float* __restrict__ KR, const float* __restrict__ KC,
    const unsigned char* __restrict__ pm,
    const short* __restrict__ Vt, short* __restrict__ ATTb) {
  __shared__ __align__(16) short KsRb[64 * 32];   // bf16 K_row, rows 56-63 zero
  __shared__ __align__(16) short KsCb[64 * 32];
  __shared__ __align__(16) short Ar[128 * 72];    // aw_row bf16, cols 56-71 zero
  __shared__ __align__(16) short Acs[128 * 56];   // aw_col bf16
  __shared__ __align__(16) short Vs[4 * 2176];    // 4 h-slabs of [32 d][68 w]
  int tid = threadIdx.x;
  int wid = tid >> 6, lane = tid & 63;
  int ln15 = lane & 15, slot = lane >> 4;
  int q0 = blockIdx.x * 128;
  int n = blockIdx.y, b = blockIdx.z;
  int bn = b * 8 + n;
  // stage K bf16 (zero-padded rows) + zero Ar pad cols
  for (int l = tid; l < 64 * 32; l += 256) {
    int row = l >> 5, d = l & 31;
    float vr = 0.f, vc = 0.f;
    if (row < 56) {
      vr = KR[((size_t)(b * 56 + row) << 8) + (n << 5) + d];
      vc = KC[((size_t)(b * 56 + row) << 8) + (n << 5) + d];
    }
    KsRb[l] = (short)f2bfu(vr);
    KsCb[l] = (short)f2bfu(vc);
  }
  for (int l = tid; l < 128 * 16; l += 256) {
    int q = l >> 4, c = 56 + (l & 15);
    Ar[q * 72 + c] = 0;
  }
  __syncthreads();
  // per-lane col masks (col = nf*16 + ln15)
  bool mr[4], mc[4];
  #pragma unroll
  for (int nf = 0; nf < 4; ++nf) {
    int c = nf * 16 + ln15;
    if (c >= 56) { mr[nf] = true; mc[nf] = true; }
    else {
      mr[nf] = pm[(size_t)b * 3136 + c] != 0;
      mc[nf] = pm[(size_t)b * 3136 + c * 56] != 0;
    }
  }
  // ---- scores + softmax per side
  #pragma unroll
  for (int side = 0; side < 2; ++side) {
    const float* Qg = side ? QC : QR;
    const short* Kb = side ? KsCb : KsRb;
    const bool* mk = side ? mc : mr;
    // A-frags from global (2 m-frags per wave)
    s16x8 qa[2];
    #pragma unroll
    for (int mf = 0; mf < 2; ++mf) {
      int q = q0 + wid * 32 + mf * 16 + ln15; if (q > 3135) q = 3135;
      const float* qp = Qg + ((size_t)(b * 3136 + q) << 8) + (n << 5) + slot * 8;
      float4 t0 = *(const float4*)qp;
      float4 t1 = *(const float4*)(qp + 4);
      s16x8 f;
      f[0] = (short)f2bfu(t0.x); f[1] = (short)f2bfu(t0.y);
      f[2] = (short)f2bfu(t0.z); f[3] = (short)f2bfu(t0.w);
      f[4] = (short)f2bfu(t1.x); f[5] = (short)f2bfu(t1.y);
      f[6] = (short)f2bfu(t1.z); f[7] = (short)f2bfu(t1.w);
      qa[mf] = f;
    }
    // B-frags from LDS
    s16x8 kb[4];
    #pragma unroll
    for (int nf = 0; nf < 4; ++nf)
      kb[nf] = *(const s16x8*)(Kb + (nf * 16 + ln15) * 32 + slot * 8);
    f32x4 sacc[2][4];
    #pragma unroll
    for (int mf = 0; mf < 2; ++mf)
      #pragma unroll
      for (int nf = 0; nf < 4; ++nf) {
        f32x4 z = {0.f, 0.f, 0.f, 0.f};
        sacc[mf][nf] = mfma16(qa[mf], kb[nf], z);
      }
    // parallel softmax over each output row (row = wid*32+mf*16+slot*4+r)
    #pragma unroll
    for (int mf = 0; mf < 2; ++mf)
      #pragma unroll
      for (int r = 0; r < 4; ++r) {
        float v[4];
        #pragma unroll
        for (int nf = 0; nf < 4; ++nf)
          v[nf] = mk[nf] ? -3.402823466e38f : sacc[mf][nf][r];
        float m = fmaxf(fmaxf(v[0], v[1]), fmaxf(v[2], v[3]));
        #pragma unroll
        for (int o = 1; o < 16; o <<= 1) m = fmaxf(m, __shfl_xor(m, o));
        float e[4], ss = 0.f;
        #pragma unroll
        for (int nf = 0; nf < 4; ++nf) {
          e[nf] = mk[nf] ? 0.f : __expf(v[nf] - m);
          ss += e[nf];
        }
        #pragma unroll
        for (int o = 1; o < 16; o <<= 1) ss += __shfl_xor(ss, o);
        float inv = 1.f / ss;
        int ql = wid * 32 + mf * 16 + slot * 4 + r;
        if (side == 0) {
          #pragma unroll
          for (int nf = 0; nf < 4; ++nf) {
            int c = nf * 16 + ln15;
            if (c < 56) Ar[ql * 72 + c] = (short)f2bfu(e[nf] * inv);
          }
        } else {
          #pragma unroll
          for (int nf = 0; nf < 4; ++nf) {
            int c = nf * 16 + ln15;
            if (c < 56) Acs[ql * 56 + c] = (short)f2bfu(e[nf] * inv);
          }
        }
      }
  }
  // ---- recombination (wave-local Ar/Acs reads; Vs needs block barrier)
  const short* Vg = Vt + (size_t)bn * 32 * 3584;
  int sd = (tid >> 3) & 31, swp = tid & 7;
  const short* vsrc = Vg + (size_t)sd * 3584 + swp * 8;
  short* vdst = Vs + sd * 68 + swp * 8;
  s16x8 pre[4];
  #pragma unroll
  for (int i = 0; i < 4; ++i)
    pre[i] = *(const s16x8*)(vsrc + (size_t)i * 64);
  #pragma unroll
  for (int i = 0; i < 4; ++i)
    *(s16x8*)(vdst + i * 2176) = pre[i];
  __syncthreads();
  s16x8 bfr[2][2];
  #pragma unroll
  for (int qf = 0; qf < 2; ++qf)
    #pragma unroll
    for (int kc = 0; kc < 2; ++kc)
      bfr[qf][kc] = *(const s16x8*)(Ar + (wid * 32 + qf * 16 + ln15) * 72
                                       + kc * 32 + slot * 8);
  f32x4 oacc[2][2] = {};
  for (int hc = 0; hc < 14; ++hc) {
    if (hc < 13) {
      #pragma unroll
      for (int i = 0; i < 4; ++i)
        pre[i] = *(const s16x8*)(vsrc + (size_t)((hc + 1) * 4 + i) * 64);
    }
    #pragma unroll
    for (int hh = 0; hh < 4; ++hh) {
      int h = hc * 4 + hh;
      s16x8 af[2][2];
      #pragma unroll
      for (int df = 0; df < 2; ++df)
        #pragma unroll
        for (int kc = 0; kc < 2; ++kc)
          af[df][kc] = *(const s16x8*)(Vs + hh * 2176 + (df * 16 + ln15) * 68
                                          + kc * 32 + slot * 8);
      #pragma unroll
      for (int qf = 0; qf < 2; ++qf) {
        float acv = __uint_as_float(
            ((unsigned)(unsigned short)Acs[(wid * 32 + qf * 16 + ln15) * 56 + h]) << 16);
        #pragma unroll
        for (int df = 0; df < 2; ++df) {
          f32x4 tmp = {0.f, 0.f, 0.f, 0.f};
          tmp = mfma16(af[df][0], bfr[qf][0], tmp);
          tmp = mfma16(af[df][1], bfr[qf][1], tmp);
          oacc[df][qf][0] += acv * tmp[0];
          oacc[df][qf][1] += acv * tmp[1];
          oacc[df][qf][2] += acv * tmp[2];
          oacc[df][qf][3] += acv * tmp[3];
        }
      }
    }
    if (hc < 13) {
      __syncthreads();
      #pragma unroll
      for (int i = 0; i < 4; ++i)
        *(s16x8*)(vdst + i * 2176) = pre[i];
      __syncthreads();
    }
  }
  // transpose out via LDS (reuse Ar), then coalesced bf16 store
  __syncthreads();
  #pragma unroll
  for (int df = 0; df < 2; ++df)
    #pragma unroll
    for (int qf = 0; qf < 2; ++qf) {
      int qi = wid * 32 + qf * 16 + ln15;
      short4 pk;
      pk.x = (short)f2bfu(oacc[df][qf][0]);
      pk.y = (short)f2bfu(oacc[df][qf][1]);
      pk.z = (short)f2bfu(oacc[df][qf][2]);
      pk.w = (short)f2bfu(oacc[df][qf][3]);
      *(short4*)(Ar + qi * 36 + df * 16 + slot * 4) = pk;
    }
  __syncthreads();
  int q = tid >> 1, half = tid & 1;
  int qg = q0 + q;
  if (qg < 3136) {
    s16x8 v = *(const s16x8*)(Ar + q * 36 + half * 16);
    *(s16x8*)(ATTb + ((size_t)(b * 3136 + qg)) * 256 + n * 32 + half * 16) = v;
  }
}

// ---------------------------------------------------------------------------
// 5) LN1: XN1 = LayerNorm(Y + X) -> fp32 + bf16
__global__ __launch_bounds__(256) void k_ln1(
    const float* __restrict__ Y, const float* __restrict__ X,
    const float* __restrict__ g, const float* __restrict__ bb,
    float* __restrict__ XN1f, short* __restrict__ XN1b) {
  int tid = threadIdx.x;
  int row = blockIdx.x * 4 + (tid >> 6);
  int ln = tid & 63;
  size_t base = (size_t)row * 256 + ln * 4;
  float4 y = *(const float4*)(Y + base);
  float4 x = *(const float4*)(X + base);
  float v0 = y.x + x.x, v1 = y.y + x.y, v2 = y.z + x.z, v3 = y.w + x.w;
  float s = v0 + v1 + v2 + v3;
  float s2 = v0 * v0 + v1 * v1 + v2 * v2 + v3 * v3;
  for (int o = 32; o; o >>= 1) { s += __shfl_xor(s, o); s2 += __shfl_xor(s2, o); }
  float m = s * (1.f / 256.f);
  float inv = rsqrtf(fmaxf(s2 * (1.f / 256.f) - m * m, 0.f) + EPSV);
  float4 gg = *(const float4*)(g + ln * 4);
  float4 bv = *(const float4*)(bb + ln * 4);
  float4 o4;
  o4.x = (v0 - m) * inv * gg.x + bv.x;
  o4.y = (v1 - m) * inv * gg.y + bv.y;
  o4.z = (v2 - m) * inv * gg.z + bv.z;
  o4.w = (v3 - m) * inv * gg.w + bv.w;
  *(float4*)(XN1f + base) = o4;
  uint2 pk;
  pk.x = (unsigned)f2bfu(o4.x) | ((unsigned)f2bfu(o4.y) << 16);
  pk.y = (unsigned)f2bfu(o4.z) | ((unsigned)f2bfu(o4.w) << 16);
  *(uint2*)(XN1b + base) = pk;
}

// 6) LN2 + transposed store to (B,C,H,W)
__global__ __launch_bounds__(256) void k_ln2t(
    const float* __restrict__ Y2, const float* __restrict__ XN1,
    const float* __restrict__ g, const float* __restrict__ bb,
    float* __restrict__ out) {
  __shared__ float VL[16][257];
  int tid = threadIdx.x;
  int r0 = blockIdx.x * 16;
  for (int l = tid; l < 16 * 256; l += 256) {
    int r = l >> 8, c = l & 255;
    VL[r][c] = Y2[(size_t)(r0 + r) * 256 + c] + XN1[(size_t)(r0 + r) * 256 + c];
  }
  __syncthreads();
  int wv = tid >> 6, ln = tid & 63;
  for (int rr = wv; rr < 16; rr += 4) {
    float s = 0.f, s2 = 0.f;
    float vv[4];
    #pragma unroll
    for (int i = 0; i < 4; ++i) {
      float v = VL[rr][ln * 4 + i];
      vv[i] = v; s += v; s2 += v * v;
    }
    for (int o = 32; o; o >>= 1) { s += __shfl_xor(s, o); s2 += __shfl_xor(s2, o); }
    float m = s * (1.f / 256.f);
    float inv = rsqrtf(fmaxf(s2 * (1.f / 256.f) - m * m, 0.f) + EPSV);
    #pragma unroll
    for (int i = 0; i < 4; ++i) {
      int c = ln * 4 + i;
      VL[rr][c] = (vv[i] - m) * inv * g[c] + bb[c];
    }
  }
  __syncthreads();
  int b = r0 / 3136;
  int hw0 = r0 % 3136;
  int r = tid & 15, cg = tid >> 4;
  for (int it = 0; it < 16; ++it) {
    int c = it * 16 + cg;
    out[(size_t)(b * 256 + c) * 3136 + hw0 + r] = VL[r][c];
  }
}

// ---------------------------------------------------------------------------
extern "C" void kernel_launch(void* const* d_in, const int* in_sizes, int n_in,
                              void* d_out, int out_size, void* d_ws, size_t ws_size,
                              hipStream_t stream) {
  const float* src = (const float*)d_in[0];
  const unsigned char* pmask = (const unsigned char*)d_in[1];
  const float* per = (const float*)d_in[2];
  const float* pec = (const float*)d_in[3];
  const float* wqr = (const float*)d_in[4];
  const float* bqr = (const float*)d_in[5];
  const float* wqc = (const float*)d_in[6];
  const float* bqc = (const float*)d_in[7];
  const float* wkr = (const float*)d_in[8];
  const float* bkr = (const float*)d_in[9];
  const float* wkc = (const float*)d_in[10];
  const float* bkc = (const float*)d_in[11];
  const float* wv  = (const float*)d_in[12];
  const float* bv  = (const float*)d_in[13];
  const float* wo  = (const float*)d_in[14];
  const float* bo  = (const float*)d_in[15];
  const float* n1g = (const float*)d_in[16];
  const float* n1b = (const float*)d_in[17];
  const float* l1w = (const float*)d_in[18];
  const float* l1b = (const float*)d_in[19];
  const float* l2w = (const float*)d_in[20];
  const float* l2b = (const float*)d_in[21];
  const float* n2g = (const float*)d_in[22];
  const float* n2b = (const float*)d_in[23];

  float* ws = (float*)d_ws;
  float* X    = ws + 0;
  short* Xb   = (short*)(ws + 1605632);
  float* QR   = ws + 2408448;
  float* QC   = ws + 4014080;
  short* Vt   = (short*)(ws + 5619712);
  short* ATTb = (short*)(ws + 12156928);
  short* FFb  = (short*)(ws + 12959744);
  float* Y    = ws + 16171008;     // also Y2
  float* XN1f = ws + 17776640;
  short* XN1b = (short*)(ws + 19382272);
  float* PRW  = ws + 20242432;
  float* PCW  = ws + 20271104;
  float* KR   = ws + 20299776;
  float* KC   = ws + 20328448;
  short* Wcat = (short*)(ws + 20357120);
  short* wob  = (short*)(ws + 20455424);
  short* l1wb = (short*)(ws + 20488192);
  short* l2wb = (short*)(ws + 20619264);
  float* out = (float*)d_out;

  k_prep0<<<2592, 256, 0, stream>>>(src, wqr, wqc, wv, wo, l1w, l2w,
                                    X, Xb, Wcat, wob, l1wb, l2wb);
  k_smallproj2<<<448, 256, 0, stream>>>(per, pec, X, wqr, wqc, wkr, wkc,
                                        bkr, bkc, PRW, PCW, KR, KC);
  k_proj64p<<<dim3(98, 12), 256, 0, stream>>>(Xb, Wcat, bqr, bqc, bv,
                                              PRW, PCW, QR, QC, Vt);
  k_fattn2<<<dim3(25, 8, 2), 256, 0, stream>>>(QR, QC, KR, KC, pmask, Vt, ATTb);
  k_gemm64p<0><<<dim3(98, 4), 256, 0, stream>>>(ATTb, wob, bo, Y, nullptr, 256, 256);
  k_ln1<<<1568, 256, 0, stream>>>(Y, X, n1g, n1b, XN1f, XN1b);
  k_gemm64p<1><<<dim3(98, 16), 256, 0, stream>>>(XN1b, l1wb, l1b, nullptr, FFb, 256, 1024);
  k_gemm64p<0><<<dim3(98, 4), 256, 0, stream>>>(FFb, l2wb, l2b, Y, nullptr, 1024, 256);
  k_ln2t<<<392, 256, 0, stream>>>(Y, XN1f, n2g, n2b, out);
}